// Round 14
// baseline (72.958 us; speedup 1.0000x reference)
//
#include <hip/hip_runtime.h>

// Wave forward: 16 channels, 208x208 window/channel, 48 steps, ONE persistent
// kernel. 6 phases x 8 substeps. Boundary exchange is PER-WAVE PIPELINED:
// 8 waves (512 thr); waves 0-3 publish one frame band each (fp16-packed 16B
// quads, sc0 sc1), wave-drain vmcnt(0), set a per-band flag (no block sync).
// All 8 waves then independently spin on ONE neighbor band flag and pull one
// halo direction strip. Bands overlap at corners so each direction needs a
// single flag. One __syncthreads at the end of the boundary.

typedef unsigned long long u64;
typedef __attribute__((ext_vector_type(4))) unsigned int u32x4;

#define GN     512
#define NMASK  511
#define NCH    16
#define NT     48
#define NM     128
#define WW     208            // window size
#define WOFF   103            // source offset inside window
#define TI     52             // tile interior
#define TS     8              // substeps per phase
#define NPHASE 6
#define HALO   16             // 2*TS
#define LT     84             // tile width (TI + 2*HALO)
#define LTS    84             // LDS row stride
#define LDSE   (LTS*LT)       // 7056
#define WCELLS (WW*WW)        // 43264
#define NTH    512            // 8 waves
#define NACT   441            // 21x21 threads x 4x4 cells = 84^2
#define NBLK   256

__device__ __forceinline__ float4 ld4(const float* p) { return *(const float4*)p; }
__device__ __forceinline__ void st4(float* p, float4 v) { *(float4*)p = v; }
__device__ __forceinline__ float2 ld2(const float* p) { return *(const float2*)p; }

__device__ __forceinline__ unsigned pack2(float c, float p) {
    _Float16 hc = (_Float16)c, hp = (_Float16)p;
    unsigned short uc, up;
    __builtin_memcpy(&uc, &hc, 2); __builtin_memcpy(&up, &hp, 2);
    return (unsigned)uc | ((unsigned)up << 16);
}
__device__ __forceinline__ float2 unpack2(unsigned v) {   // -> (C, P)
    unsigned short uc = (unsigned short)(v & 0xffffu), up = (unsigned short)(v >> 16);
    _Float16 hc, hp;
    __builtin_memcpy(&hc, &uc, 2); __builtin_memcpy(&hp, &up, 2);
    return make_float2((float)hc, (float)hp);
}

// 16B coherent (cross-XCD) store/load: same sc0 sc1 flags as agent atomics.
__device__ __forceinline__ void st_coh(unsigned* p, u32x4 v) {
    asm volatile("global_store_dwordx4 %0, %1, off sc0 sc1"
                 :: "v"(p), "v"(v) : "memory");
}
__device__ __forceinline__ u32x4 ld_coh(const unsigned* p) {
    u32x4 r;
    asm volatile("global_load_dwordx4 %0, %1, off sc0 sc1"
                 : "=v"(r) : "v"(p) : "memory");
    return r;
}

__device__ __forceinline__ float kcoef(const float* __restrict__ x, int gi, int gj) {
    float xp;
    if (gi < 55 || gi >= 457 || gj < 55 || gj >= 457)
        xp = 1e-6f;                                   // ABC pad
    else if (gi >= 128 && gi < 384 && gj >= 128 && gj < 384)
        xp = x[(gi - 128) * 256 + (gj - 128)];
    else
        xp = 1.5f;                                    // bg pad
    float t = 0.2f * xp;
    return t * t;
}

__device__ __forceinline__ int tile_sdist(int ti, int tj) {
    int lo = ti * TI - HALO, hi = lo + LT - 1;
    int di = WOFF < lo ? lo - WOFF : (WOFF > hi ? WOFF - hi : 0);
    lo = tj * TI - HALO; hi = lo + LT - 1;
    int dj = WOFF < lo ? lo - WOFF : (WOFF > hi ? WOFF - hi : 0);
    return di > dj ? di : dj;
}
__device__ __forceinline__ bool tile_live(int ti, int tj, int ph) {
    return tile_sdist(ti, tj) <= 2 * (ph * TS + TS) + 4;
}

__global__ __launch_bounds__(NTH, 1)
void persist_kernel(const float* __restrict__ x,
                    const float* __restrict__ src,
                    const int* __restrict__ meas,
                    const int* __restrict__ trans,
                    int* __restrict__ flags,      // [(NPHASE-1)*NBLK*4]
                    unsigned* __restrict__ GA, unsigned* __restrict__ GB,
                    float* __restrict__ out)
{
    __shared__ float lds0[LDSE];
    __shared__ float lds1[LDSE];
    const int tid  = threadIdx.x;
    const int b    = blockIdx.x;
    const int r    = b & 15;          // channel
    const int tile = b >> 4;
    const int tI   = tile >> 2, tJ = tile & 3;
    const int ri0  = tI * TI - HALO;
    const int rj0  = tJ * TI - HALO;
    const int wid  = tid >> 6;        // wave id 0..7
    const int lane = tid & 63;

    const bool active = tid < NACT;
    const int ty = tid / 21, tx = tid - 21 * (tid / 21);
    const int li0 = 4 * ty, lj0 = 4 * tx;
    const bool inner = active && tx >= 4 && tx <= 16 && ty >= 4 && ty <= 16;

    for (int q = tid; q < LDSE / 4; q += NTH) {
        st4(&lds0[q * 4], make_float4(0.f, 0.f, 0.f, 0.f));
        st4(&lds1[q * 4], make_float4(0.f, 0.f, 0.f, 0.f));
    }

    const int trv = trans[r];
    const int ox = (trv >> 9) - WOFF, oy = (trv & NMASK) - WOFF;

    float C[16], P[16], K[16];
    #pragma unroll
    for (int i = 0; i < 16; ++i) { C[i] = 0.f; P[i] = 0.f; K[i] = 0.f; }

    int offT2 = 0, offT1 = 0, offB1 = 0, offB2 = 0;
    int offLp[4] = {0,0,0,0}, offRp[4] = {0,0,0,0}, offC[4] = {0,0,0,0};
    unsigned smask = 0;
    if (active) {
        #pragma unroll
        for (int rr = 0; rr < 4; ++rr) {
            int wr = ri0 + li0 + rr;
            #pragma unroll
            for (int cc = 0; cc < 4; ++cc) {
                int wc = rj0 + lj0 + cc;
                K[rr*4+cc] = kcoef(x, (ox + wr) & NMASK, (oy + wc) & NMASK);
            }
        }
        int rT2 = li0 - 2 < 0 ? 0 : li0 - 2;
        int rT1 = li0 - 1 < 0 ? 0 : li0 - 1;
        int rB1 = li0 + 4 > LT - 1 ? LT - 1 : li0 + 4;
        int rB2 = li0 + 5 > LT - 1 ? LT - 1 : li0 + 5;
        offT2 = rT2 * LTS + lj0;  offT1 = rT1 * LTS + lj0;
        offB1 = rB1 * LTS + lj0;  offB2 = rB2 * LTS + lj0;
        #pragma unroll
        for (int rr = 0; rr < 4; ++rr) {
            int base = (li0 + rr) * LTS + lj0;
            offC[rr] = base;
            int ol = base - 2;  if (ol < 0) ol = 0;           // 8B aligned
            int orr = base + 4; if (orr > LDSE - 2) orr = LDSE - 2;
            offLp[rr] = ol; offRp[rr] = orr;
        }
        int si = (WOFF - ri0) - li0, sj = (WOFF - rj0) - lj0;
        if (si >= 0 && si < 4 && sj >= 0 && sj < 4) smask = 1u << (si * 4 + sj);
    }

    bool mvalid = false; int mlds = 0; float* mout = nullptr;
    if (tid < NM) {
        int mc = meas[tid];
        int mi = ((mc >> 9)    - ox) & NMASK;
        int mj = ((mc & NMASK) - oy) & NMASK;
        int li = mi - ri0, lj = mj - rj0;
        mvalid = (li >= HALO && li < HALO + TI && lj >= HALO && lj < HALO + TI);
        mlds = li * LTS + lj;
        mout = out + (size_t)(r * NM + tid) * NT;
    }

    __syncthreads();

    auto step1 = [&](float (&A)[16], float (&B)[16],
                     const float* rd, float* wb, float sval, int jj) {
        if (active) {
            float t2[4], t1[4], b1a[4], b2a[4];
            float4 v;
            v = ld4(rd + offT2); t2[0]=v.x;  t2[1]=v.y;  t2[2]=v.z;  t2[3]=v.w;
            v = ld4(rd + offT1); t1[0]=v.x;  t1[1]=v.y;  t1[2]=v.z;  t1[3]=v.w;
            v = ld4(rd + offB1); b1a[0]=v.x; b1a[1]=v.y; b1a[2]=v.z; b1a[3]=v.w;
            v = ld4(rd + offB2); b2a[0]=v.x; b2a[1]=v.y; b2a[2]=v.z; b2a[3]=v.w;
            float2 lp[4], rp[4];
            #pragma unroll
            for (int rr = 0; rr < 4; ++rr) {
                lp[rr] = ld2(rd + offLp[rr]);   // cols -2,-1
                rp[rr] = ld2(rd + offRp[rr]);   // cols +4,+5
            }
            #pragma unroll
            for (int rr = 0; rr < 4; ++rr) {
                float h[8];
                h[0]=lp[rr].x; h[1]=lp[rr].y;
                h[2]=B[rr*4+0]; h[3]=B[rr*4+1]; h[4]=B[rr*4+2]; h[5]=B[rr*4+3];
                h[6]=rp[rr].x; h[7]=rp[rr].y;
                #pragma unroll
                for (int cc = 0; cc < 4; ++cc) {
                    float vm2 = (rr == 0) ? t2[cc]  : (rr == 1) ? t1[cc]  : B[(rr-2)*4+cc];
                    float vm1 = (rr == 0) ? t1[cc]  : B[(rr-1)*4+cc];
                    float vp1 = (rr == 3) ? b1a[cc] : B[(rr+1)*4+cc];
                    float vp2 = (rr == 3) ? b2a[cc] : (rr == 2) ? b1a[cc] : B[(rr+2)*4+cc];
                    float c0  = h[cc+2];
                    float lap = (16.f * (h[cc+1] + h[cc+3] + vm1 + vp1)
                                 - (h[cc] + h[cc+4] + vm2 + vp2)
                                 - 60.f * c0) * (1.f / 12.f);
                    float pn = 2.f * c0 - A[rr*4+cc] + K[rr*4+cc] * lap;
                    if (smask & (1u << (rr*4+cc))) pn += sval;
                    A[rr*4+cc] = pn;
                }
                st4(wb + offC[rr],
                    make_float4(A[rr*4+0], A[rr*4+1], A[rr*4+2], A[rr*4+3]));
            }
        }
        __syncthreads();
        if (mvalid) mout[jj] = wb[mlds];
    };

    for (int ph = 0; ph < NPHASE; ++ph) {
        const int J = ph * TS;
        const bool liveSelf = tile_live(tI, tJ, ph);
        unsigned* Wp = ((ph & 1) ? GB : GA) + (size_t)r * WCELLS;
        const bool bnd = ph < NPHASE - 1;
        if (liveSelf) {
            float sv[TS];
            #pragma unroll
            for (int s = 0; s < TS; ++s) sv[s] = 0.09f * src[J + s];
            step1(P, C, lds0, lds1, sv[0], J + 0);
            step1(C, P, lds1, lds0, sv[1], J + 1);
            step1(P, C, lds0, lds1, sv[2], J + 2);
            step1(C, P, lds1, lds0, sv[3], J + 3);
            step1(P, C, lds0, lds1, sv[4], J + 4);
            step1(C, P, lds1, lds0, sv[5], J + 5);
            step1(P, C, lds0, lds1, sv[6], J + 6);
            step1(C, P, lds1, lds0, sv[7], J + 7);
            // lds0 = f_{J+7} (valid [16,68)^2), lds1 = f_{J+6}
        }
        if (bnd) {
            const bool liveNext = tile_live(tI, tJ, ph + 1);
            // ---- publish: wave w < 4 publishes band w, wave-drains, flags
            if (liveSelf && wid < 4) {
                #pragma unroll
                for (int k = 0; k < 4; ++k) {
                    int q = lane + 64 * k;
                    if (q < 208) {
                        int row, col;
                        if (wid == 0)      { int qr = q / 13; row = 16 + qr; col = 16 + 4 * (q - 13 * qr); }
                        else if (wid == 1) { int qr = q / 13; row = 52 + qr; col = 16 + 4 * (q - 13 * qr); }
                        else if (wid == 2) { row = 16 + (q >> 2); col = 16 + 4 * (q & 3); }
                        else               { row = 16 + (q >> 2); col = 52 + 4 * (q & 3); }
                        int l = row * LTS + col;
                        u32x4 v;
                        v.x = pack2(lds0[l],     lds1[l]);
                        v.y = pack2(lds0[l + 1], lds1[l + 1]);
                        v.z = pack2(lds0[l + 2], lds1[l + 2]);
                        v.w = pack2(lds0[l + 3], lds1[l + 3]);
                        st_coh(&Wp[(ri0 + row) * WW + (rj0 + col)], v);
                    }
                }
                asm volatile("s_waitcnt vmcnt(0)" ::: "memory");  // wave-level drain
                if (lane == 0)
                    __hip_atomic_store(&flags[(ph * NBLK + b) * 4 + wid], 1,
                                       __ATOMIC_RELAXED, __HIP_MEMORY_SCOPE_AGENT);
            }
            // ---- consume: each wave handles one halo direction
            if (liveNext) {
                int dti, dtj, fb;
                if      (wid == 0) { dti = -1; dtj =  0; fb = 1; }
                else if (wid == 1) { dti =  1; dtj =  0; fb = 0; }
                else if (wid == 2) { dti =  0; dtj = -1; fb = 3; }
                else if (wid == 3) { dti =  0; dtj =  1; fb = 2; }
                else if (wid == 4) { dti = -1; dtj = -1; fb = 1; }
                else if (wid == 5) { dti = -1; dtj =  1; fb = 1; }
                else if (wid == 6) { dti =  1; dtj = -1; fb = 0; }
                else               { dti =  1; dtj =  1; fb = 0; }
                int nti = tI + dti, ntj = tJ + dtj;
                const bool has = ((unsigned)nti < 4u) && ((unsigned)ntj < 4u) &&
                                 tile_live(nti, ntj, ph);
                if (has) {
                    int* f = &flags[(ph * NBLK + ((((nti << 2) | ntj) << 4) | r)) * 4 + fb];
                    while (!__hip_atomic_load(f, __ATOMIC_RELAXED,
                                              __HIP_MEMORY_SCOPE_AGENT)) {}
                }
                const int NQ = (wid < 4) ? 208 : 64;
                u32x4 vv[4]; int ll[4];
                #pragma unroll
                for (int k = 0; k < 4; ++k) {
                    vv[k].x = vv[k].y = vv[k].z = vv[k].w = 0u; ll[k] = -1;
                    int q = lane + 64 * k;
                    if (q < NQ) {
                        int row, col;
                        if      (wid == 0) { int qr = q / 13; row = qr;            col = 16 + 4 * (q - 13 * qr); }
                        else if (wid == 1) { int qr = q / 13; row = 68 + qr;       col = 16 + 4 * (q - 13 * qr); }
                        else if (wid == 2) { row = 16 + (q >> 2); col = 4 * (q & 3); }
                        else if (wid == 3) { row = 16 + (q >> 2); col = 68 + 4 * (q & 3); }
                        else if (wid == 4) { row = (q >> 2);      col = 4 * (q & 3); }
                        else if (wid == 5) { row = (q >> 2);      col = 68 + 4 * (q & 3); }
                        else if (wid == 6) { row = 68 + (q >> 2); col = 4 * (q & 3); }
                        else               { row = 68 + (q >> 2); col = 68 + 4 * (q & 3); }
                        ll[k] = row * LTS + col;
                        if (has)
                            vv[k] = ld_coh(&Wp[(ri0 + row) * WW + (rj0 + col)]);
                    }
                }
                if (has) asm volatile("s_waitcnt vmcnt(0)" ::: "memory");
                #pragma unroll
                for (int k = 0; k < 4; ++k) {
                    if (ll[k] >= 0) {
                        float4 f0, f1;
                        if (has) {
                            float2 a = unpack2(vv[k].x), bq = unpack2(vv[k].y);
                            float2 c2 = unpack2(vv[k].z), d = unpack2(vv[k].w);
                            f0 = make_float4(a.x, bq.x, c2.x, d.x);
                            f1 = make_float4(a.y, bq.y, c2.y, d.y);
                        } else {
                            f0 = make_float4(0.f, 0.f, 0.f, 0.f); f1 = f0;
                        }
                        st4(&lds0[ll[k]], f0);
                        st4(&lds1[ll[k]], f1);
                    }
                }
            }
            __syncthreads();      // all directions pulled, all bands published
            if (liveNext && active && !inner) {   // ring threads refill regs
                #pragma unroll
                for (int rr = 0; rr < 4; ++rr) {
                    float4 vc = ld4(&lds0[offC[rr]]);
                    float4 vp = ld4(&lds1[offC[rr]]);
                    C[rr*4+0]=vc.x; C[rr*4+1]=vc.y; C[rr*4+2]=vc.z; C[rr*4+3]=vc.w;
                    P[rr*4+0]=vp.x; P[rr*4+1]=vp.y; P[rr*4+2]=vp.z; P[rr*4+3]=vp.w;
                }
            }
        }
    }
}

extern "C" void kernel_launch(void* const* d_in, const int* in_sizes, int n_in,
                              void* d_out, int out_size, void* d_ws, size_t ws_size,
                              hipStream_t stream)
{
    const float* x     = (const float*)d_in[0];
    const float* src   = (const float*)d_in[1];
    const int*   meas  = (const int*)d_in[2];
    const int*   trans = (const int*)d_in[3];
    float* outp = (float*)d_out;

    int*      flags = (int*)d_ws;                       // 5*256*4 ints = 20 KB
    unsigned* GA = (unsigned*)((char*)d_ws + 32768);    // 16B-aligned
    unsigned* GB = GA + (size_t)NCH * WCELLS;

    hipMemsetAsync(flags, 0, (NPHASE - 1) * NBLK * 4 * sizeof(int), stream);
    hipMemsetAsync(outp, 0, (size_t)out_size * sizeof(float), stream);

    persist_kernel<<<NBLK, NTH, 0, stream>>>(x, src, meas, trans, flags,
                                             GA, GB, outp);
}

// Round 15
// 72.157 us; speedup vs baseline: 1.0111x; 1.0111x over previous
//
#include <hip/hip_runtime.h>

// Wave forward: 16 channels, 208x208 window/channel, 48 steps, ONE persistent
// kernel. 6 phases x 8 substeps; r13 boundary protocol (3x3-neighborhood
// agent-scope flags; fp16-packed 16B-quad halo exchange, sc0 sc1).
// THIS ROUND: padded-group LDS layout. Each 4-col thread group is stored with
// stride 6 floats: E(row,col) = row*126 + (col>>2)*6 + (col&3). Lane bank
// bases become 6*tx mod 32 (all-distinct except a free 2-way) -> kills the
// 3-way b128 conflicts. All stencil LDS ops are aligned ds_*_b64.

typedef unsigned long long u64;
typedef __attribute__((ext_vector_type(4))) unsigned int u32x4;

#define GN     512
#define NMASK  511
#define NCH    16
#define NT     48
#define NM     128
#define WW     208            // window size
#define WOFF   103            // source offset inside window
#define TI     52             // tile interior
#define TS     8              // substeps per phase
#define NPHASE 6
#define HALO   16             // 2*TS
#define LT     84             // tile width (TI + 2*HALO)
#define GS     6              // padded group stride (4 data + 2 pad floats)
#define LROW   126            // 21 groups * GS
#define LDSE   (LROW*LT)      // 10584 floats = 42.3 KB per buffer
#define WCELLS (WW*WW)        // 43264
#define NTH    448            // 7 waves
#define NACT   441            // 21x21 threads x 4x4 cells = 84^2
#define NBLK   256
#define FQUAD  576            // frame cell-quads (2304/4)
#define FQUAD_A 416           // rows 16-31,52-67 x cols 16-67 (13 quads/row)
#define NQUAD  1088           // halo cell-quads (4352/4)
#define NQUAD_TB 672          // rows 0-15,68-83 x 21 quads/row
#define NPULLQ 3              // ceil(NQUAD / NTH)

__device__ __forceinline__ float4 ld4(const float* p) { return *(const float4*)p; }
__device__ __forceinline__ void st4(float* p, float4 v) { *(float4*)p = v; }
__device__ __forceinline__ float2 ld2(const float* p) { return *(const float2*)p; }
__device__ __forceinline__ void st2(float* p, float2 v) { *(float2*)p = v; }

// padded-group LDS element index (col in [0,84))
__device__ __forceinline__ int Eidx(int row, int col) {
    return row * LROW + (col >> 2) * GS + (col & 3);
}

__device__ __forceinline__ unsigned pack2(float c, float p) {
    _Float16 hc = (_Float16)c, hp = (_Float16)p;
    unsigned short uc, up;
    __builtin_memcpy(&uc, &hc, 2); __builtin_memcpy(&up, &hp, 2);
    return (unsigned)uc | ((unsigned)up << 16);
}
__device__ __forceinline__ float2 unpack2(unsigned v) {   // -> (C, P)
    unsigned short uc = (unsigned short)(v & 0xffffu), up = (unsigned short)(v >> 16);
    _Float16 hc, hp;
    __builtin_memcpy(&hc, &uc, 2); __builtin_memcpy(&hp, &up, 2);
    return make_float2((float)hc, (float)hp);
}

// 16B coherent (cross-XCD) store/load: same sc0 sc1 flags as agent atomics.
__device__ __forceinline__ void st_coh(unsigned* p, u32x4 v) {
    asm volatile("global_store_dwordx4 %0, %1, off sc0 sc1"
                 :: "v"(p), "v"(v) : "memory");
}
__device__ __forceinline__ u32x4 ld_coh(const unsigned* p) {
    u32x4 r;
    asm volatile("global_load_dwordx4 %0, %1, off sc0 sc1"
                 : "=v"(r) : "v"(p) : "memory");
    return r;
}

__device__ __forceinline__ float kcoef(const float* __restrict__ x, int gi, int gj) {
    float xp;
    if (gi < 55 || gi >= 457 || gj < 55 || gj >= 457)
        xp = 1e-6f;                                   // ABC pad
    else if (gi >= 128 && gi < 384 && gj >= 128 && gj < 384)
        xp = x[(gi - 128) * 256 + (gj - 128)];
    else
        xp = 1.5f;                                    // bg pad
    float t = 0.2f * xp;
    return t * t;
}

__device__ __forceinline__ int tile_sdist(int ti, int tj) {
    int lo = ti * TI - HALO, hi = lo + LT - 1;
    int di = WOFF < lo ? lo - WOFF : (WOFF > hi ? WOFF - hi : 0);
    lo = tj * TI - HALO; hi = lo + LT - 1;
    int dj = WOFF < lo ? lo - WOFF : (WOFF > hi ? WOFF - hi : 0);
    return di > dj ? di : dj;
}
__device__ __forceinline__ bool tile_live(int ti, int tj, int ph) {
    return tile_sdist(ti, tj) <= 2 * (ph * TS + TS) + 4;
}

__global__ __launch_bounds__(NTH, 1)
void persist_kernel(const float* __restrict__ x,
                    const float* __restrict__ src,
                    const int* __restrict__ meas,
                    const int* __restrict__ trans,
                    int* __restrict__ flags,
                    unsigned* __restrict__ GA, unsigned* __restrict__ GB,
                    float* __restrict__ out)
{
    __shared__ float lds0[LDSE];
    __shared__ float lds1[LDSE];
    const int tid  = threadIdx.x;
    const int b    = blockIdx.x;
    const int r    = b & 15;          // channel
    const int tile = b >> 4;
    const int tI   = tile >> 2, tJ = tile & 3;
    const int ri0  = tI * TI - HALO;
    const int rj0  = tJ * TI - HALO;

    const bool active = tid < NACT;
    const int ty = tid / 21, tx = tid - 21 * (tid / 21);
    const int li0 = 4 * ty, lj0 = 4 * tx;
    const bool inner = active && tx >= 4 && tx <= 16 && ty >= 4 && ty <= 16;

    // zero BOTH buffers (incl. pad floats; dead->live blocks rely on zeros)
    for (int q = tid; q < LDSE / 4; q += NTH) {
        st4(&lds0[q * 4], make_float4(0.f, 0.f, 0.f, 0.f));
        st4(&lds1[q * 4], make_float4(0.f, 0.f, 0.f, 0.f));
    }

    const int trv = trans[r];
    const int ox = (trv >> 9) - WOFF, oy = (trv & NMASK) - WOFF;

    float C[16], P[16], K[16];
    #pragma unroll
    for (int i = 0; i < 16; ++i) { C[i] = 0.f; P[i] = 0.f; K[i] = 0.f; }

    int offT2 = 0, offT1 = 0, offB1 = 0, offB2 = 0;
    int offLp[4] = {0,0,0,0}, offRp[4] = {0,0,0,0}, offC[4] = {0,0,0,0};
    unsigned smask = 0;
    if (active) {
        #pragma unroll
        for (int rr = 0; rr < 4; ++rr) {
            int wr = ri0 + li0 + rr;
            #pragma unroll
            for (int cc = 0; cc < 4; ++cc) {
                int wc = rj0 + lj0 + cc;
                K[rr*4+cc] = kcoef(x, (ox + wr) & NMASK, (oy + wc) & NMASK);
            }
        }
        int rT2 = li0 - 2 < 0 ? 0 : li0 - 2;
        int rT1 = li0 - 1 < 0 ? 0 : li0 - 1;
        int rB1 = li0 + 4 > LT - 1 ? LT - 1 : li0 + 4;
        int rB2 = li0 + 5 > LT - 1 ? LT - 1 : li0 + 5;
        const int gb = tx * GS;                       // own group offset
        offT2 = rT2 * LROW + gb;  offT1 = rT1 * LROW + gb;
        offB1 = rB1 * LROW + gb;  offB2 = rB2 * LROW + gb;
        #pragma unroll
        for (int rr = 0; rr < 4; ++rr) {
            int rowb = (li0 + rr) * LROW;
            offC[rr]  = rowb + gb;
            offLp[rr] = rowb + (tx > 0  ? (tx - 1) * GS + 2 : gb);  // cols -2,-1
            offRp[rr] = rowb + (tx < 20 ? (tx + 1) * GS     : gb);  // cols +4,+5
        }
        int si = (WOFF - ri0) - li0, sj = (WOFF - rj0) - lj0;
        if (si >= 0 && si < 4 && sj >= 0 && sj < 4) smask = 1u << (si * 4 + sj);
    }

    bool mvalid = false; int mlds = 0; float* mout = nullptr;
    if (tid < NM) {
        int mc = meas[tid];
        int mi = ((mc >> 9)    - ox) & NMASK;
        int mj = ((mc & NMASK) - oy) & NMASK;
        int li = mi - ri0, lj = mj - rj0;
        mvalid = (li >= HALO && li < HALO + TI && lj >= HALO && lj < HALO + TI);
        if (mvalid) mlds = Eidx(li, lj);
        mout = out + (size_t)(r * NM + tid) * NT;
    }

    __syncthreads();

    auto step1 = [&](float (&A)[16], float (&B)[16],
                     const float* rd, float* wb, float sval, int jj) {
        if (active) {
            float t2[4], t1[4], b1a[4], b2a[4];
            float2 v;
            v = ld2(rd + offT2);     t2[0]=v.x;  t2[1]=v.y;
            v = ld2(rd + offT2 + 2); t2[2]=v.x;  t2[3]=v.y;
            v = ld2(rd + offT1);     t1[0]=v.x;  t1[1]=v.y;
            v = ld2(rd + offT1 + 2); t1[2]=v.x;  t1[3]=v.y;
            v = ld2(rd + offB1);     b1a[0]=v.x; b1a[1]=v.y;
            v = ld2(rd + offB1 + 2); b1a[2]=v.x; b1a[3]=v.y;
            v = ld2(rd + offB2);     b2a[0]=v.x; b2a[1]=v.y;
            v = ld2(rd + offB2 + 2); b2a[2]=v.x; b2a[3]=v.y;
            float2 lp[4], rp[4];
            #pragma unroll
            for (int rr = 0; rr < 4; ++rr) {
                lp[rr] = ld2(rd + offLp[rr]);   // cols -2,-1
                rp[rr] = ld2(rd + offRp[rr]);   // cols +4,+5
            }
            #pragma unroll
            for (int rr = 0; rr < 4; ++rr) {
                float h[8];
                h[0]=lp[rr].x; h[1]=lp[rr].y;
                h[2]=B[rr*4+0]; h[3]=B[rr*4+1]; h[4]=B[rr*4+2]; h[5]=B[rr*4+3];
                h[6]=rp[rr].x; h[7]=rp[rr].y;
                #pragma unroll
                for (int cc = 0; cc < 4; ++cc) {
                    float vm2 = (rr == 0) ? t2[cc]  : (rr == 1) ? t1[cc]  : B[(rr-2)*4+cc];
                    float vm1 = (rr == 0) ? t1[cc]  : B[(rr-1)*4+cc];
                    float vp1 = (rr == 3) ? b1a[cc] : B[(rr+1)*4+cc];
                    float vp2 = (rr == 3) ? b2a[cc] : (rr == 2) ? b1a[cc] : B[(rr+2)*4+cc];
                    float c0  = h[cc+2];
                    float lap = (16.f * (h[cc+1] + h[cc+3] + vm1 + vp1)
                                 - (h[cc] + h[cc+4] + vm2 + vp2)
                                 - 60.f * c0) * (1.f / 12.f);
                    float pn = 2.f * c0 - A[rr*4+cc] + K[rr*4+cc] * lap;
                    if (smask & (1u << (rr*4+cc))) pn += sval;
                    A[rr*4+cc] = pn;
                }
                st2(wb + offC[rr],     make_float2(A[rr*4+0], A[rr*4+1]));
                st2(wb + offC[rr] + 2, make_float2(A[rr*4+2], A[rr*4+3]));
            }
        }
        __syncthreads();
        if (mvalid) mout[jj] = wb[mlds];
    };

    for (int ph = 0; ph < NPHASE; ++ph) {
        const int J = ph * TS;
        const bool liveSelf = tile_live(tI, tJ, ph);
        unsigned* Wp = ((ph & 1) ? GB : GA) + (size_t)r * WCELLS;
        const bool bnd = ph < NPHASE - 1;
        if (liveSelf) {
            float sv[TS];
            #pragma unroll
            for (int s = 0; s < TS; ++s) sv[s] = 0.09f * src[J + s];
            step1(P, C, lds0, lds1, sv[0], J + 0);
            step1(C, P, lds1, lds0, sv[1], J + 1);
            step1(P, C, lds0, lds1, sv[2], J + 2);
            step1(C, P, lds1, lds0, sv[3], J + 3);
            step1(P, C, lds0, lds1, sv[4], J + 4);
            step1(C, P, lds1, lds0, sv[5], J + 5);
            step1(P, C, lds0, lds1, sv[6], J + 6);
            step1(C, P, lds1, lds0, sv[7], J + 7);
            // lds0 = f_{J+7} (valid [16,68)^2), lds1 = f_{J+6}
        }
        if (bnd) {
            if (liveSelf) {   // publish frame as fp16-packed cell QUADS (16B)
                for (int pf = tid; pf < FQUAD; pf += NTH) {
                    int row, col;
                    if (pf < FQUAD_A) {
                        int rA = pf / 13;
                        row = 16 + (rA < 16 ? rA : rA + 20);
                        col = 16 + 4 * (pf - 13 * rA);
                    } else {
                        int p2 = pf - FQUAD_A;
                        int rB = p2 >> 3;
                        int c  = p2 & 7;
                        row = 32 + rB;
                        col = c < 4 ? 16 + 4 * c : 4 * c + 36;   // 52..64
                    }
                    int l = row * LROW + (col >> 2) * GS;
                    u32x4 v;
                    v.x = pack2(lds0[l],     lds1[l]);
                    v.y = pack2(lds0[l + 1], lds1[l + 1]);
                    v.z = pack2(lds0[l + 2], lds1[l + 2]);
                    v.w = pack2(lds0[l + 3], lds1[l + 3]);
                    int gw = (ri0 + row) * WW + (rj0 + col);     // %4 == 0
                    st_coh(&Wp[gw], v);
                }
                asm volatile("s_waitcnt vmcnt(0)" ::: "memory");
            }
            __syncthreads();
            if (liveSelf && tid == 0)
                __hip_atomic_store(&flags[ph * NBLK + b], 1,
                                   __ATOMIC_RELAXED, __HIP_MEMORY_SCOPE_AGENT);
            const bool liveNext = tile_live(tI, tJ, ph + 1);
            if (liveNext && tid < 9 && tid != 4) {     // spin on live neighbors
                int nti = tI + tid / 3 - 1, ntj = tJ + tid % 3 - 1;
                if ((unsigned)nti < 4u && (unsigned)ntj < 4u &&
                    tile_live(nti, ntj, ph)) {
                    int* f = &flags[ph * NBLK + ((((nti << 2) | ntj) << 4) | r)];
                    while (!__hip_atomic_load(f, __ATOMIC_RELAXED,
                                              __HIP_MEMORY_SCOPE_AGENT)) {}
                }
            }
            __syncthreads();
            if (liveNext) {
                // batched pull of halo quads (static reg indices), then LDS b64s
                u32x4 vv[NPULLQ]; int ll[NPULLQ];
                #pragma unroll
                for (int k = 0; k < NPULLQ; ++k) {
                    vv[k].x = vv[k].y = vv[k].z = vv[k].w = 0u; ll[k] = -1;
                    int p = tid + k * NTH;
                    if (p < NQUAD) {
                        int row, col;
                        if (p < NQUAD_TB) {
                            int rT = p / 21;
                            row = rT < 16 ? rT : rT + 52;
                            col = 4 * (p - 21 * rT);
                        } else {
                            int p2 = p - NQUAD_TB;
                            int rM = p2 >> 3;
                            int c  = p2 & 7;
                            row = 16 + rM;
                            col = c < 4 ? 4 * c : 4 * c + 52;    // 68..80
                        }
                        ll[k] = row * LROW + (col >> 2) * GS;
                        int nti = tI + (row < HALO ? -1 : (row >= HALO + TI ? 1 : 0));
                        int ntj = tJ + (col < HALO ? -1 : (col >= HALO + TI ? 1 : 0));
                        if ((unsigned)nti < 4u && (unsigned)ntj < 4u &&
                            tile_live(nti, ntj, ph)) {
                            int gw = (ri0 + row) * WW + (rj0 + col);
                            vv[k] = ld_coh(&Wp[gw]);
                        } else {
                            ll[k] = -ll[k] - 2;   // mark zero-fill (encode)
                        }
                    }
                }
                asm volatile("s_waitcnt vmcnt(0)" ::: "memory");
                #pragma unroll
                for (int k = 0; k < NPULLQ; ++k) {
                    int l = ll[k];
                    bool zf = false;
                    if (l < -1) { l = -l - 2; zf = true; }
                    if (l >= 0) {
                        float2 a0, a1, b0, b1;
                        if (zf) {
                            a0 = make_float2(0.f, 0.f); a1 = a0; b0 = a0; b1 = a0;
                        } else {
                            float2 a = unpack2(vv[k].x), bq = unpack2(vv[k].y);
                            float2 c2 = unpack2(vv[k].z), d = unpack2(vv[k].w);
                            a0 = make_float2(a.x, bq.x); a1 = make_float2(c2.x, d.x);
                            b0 = make_float2(a.y, bq.y); b1 = make_float2(c2.y, d.y);
                        }
                        st2(&lds0[l],     a0);
                        st2(&lds0[l + 2], a1);
                        st2(&lds1[l],     b0);
                        st2(&lds1[l + 2], b1);
                    }
                }
                __syncthreads();
                if (active && !inner) {   // ring threads refill regs from LDS
                    #pragma unroll
                    for (int rr = 0; rr < 4; ++rr) {
                        float2 c0 = ld2(&lds0[offC[rr]]);
                        float2 c1 = ld2(&lds0[offC[rr] + 2]);
                        float2 p0 = ld2(&lds1[offC[rr]]);
                        float2 p1 = ld2(&lds1[offC[rr] + 2]);
                        C[rr*4+0]=c0.x; C[rr*4+1]=c0.y; C[rr*4+2]=c1.x; C[rr*4+3]=c1.y;
                        P[rr*4+0]=p0.x; P[rr*4+1]=p0.y; P[rr*4+2]=p1.x; P[rr*4+3]=p1.y;
                    }
                }
            }
        }
    }
}

extern "C" void kernel_launch(void* const* d_in, const int* in_sizes, int n_in,
                              void* d_out, int out_size, void* d_ws, size_t ws_size,
                              hipStream_t stream)
{
    const float* x     = (const float*)d_in[0];
    const float* src   = (const float*)d_in[1];
    const int*   meas  = (const int*)d_in[2];
    const int*   trans = (const int*)d_in[3];
    float* outp = (float*)d_out;

    int*      flags = (int*)d_ws;                       // NPHASE*NBLK ints
    unsigned* GA = (unsigned*)((char*)d_ws + 8192);     // 16B-aligned
    unsigned* GB = GA + (size_t)NCH * WCELLS;

    hipMemsetAsync(flags, 0, NPHASE * NBLK * sizeof(int), stream);
    hipMemsetAsync(outp, 0, (size_t)out_size * sizeof(float), stream);

    persist_kernel<<<NBLK, NTH, 0, stream>>>(x, src, meas, trans, flags,
                                             GA, GB, outp);
}

// Round 16
// 69.967 us; speedup vs baseline: 1.0427x; 1.0313x over previous
//
#include <hip/hip_runtime.h>

// Wave forward: 16 channels, 208x208 window/channel, 48 steps, ONE persistent
// kernel (r13 structure: 6 phases x 8 substeps, 3x3-neighborhood agent-flag
// sync, fp16-packed 16B-quad halo exchange via sc0 sc1 loads/stores).
// THIS ROUND: out[] is zeroed in-kernel (disjoint single-writer ownership):
// meas owners write every step (0 when tile dead); tile-0 of each channel
// zeroes out-of-window meas entries. Drops the out-memset dispatch.

typedef unsigned long long u64;
typedef __attribute__((ext_vector_type(4))) unsigned int u32x4;

#define GN     512
#define NMASK  511
#define NCH    16
#define NT     48
#define NM     128
#define WW     208            // window size
#define WOFF   103            // source offset inside window
#define TI     52             // tile interior
#define TS     8              // substeps per phase
#define NPHASE 6
#define HALO   16             // 2*TS
#define LT     84             // tile width (TI + 2*HALO)
#define LTS    84             // LDS row stride
#define LDSE   (LTS*LT)       // 7056
#define WCELLS (WW*WW)        // 43264
#define NTH    448            // 7 waves
#define NACT   441            // 21x21 threads x 4x4 cells = 84^2
#define NBLK   256
#define FQUAD  576            // frame cell-quads (2304/4)
#define FQUAD_A 416           // rows 16-31,52-67 x cols 16-67 (13 quads/row)
#define NQUAD  1088           // halo cell-quads (4352/4)
#define NQUAD_TB 672          // rows 0-15,68-83 x 21 quads/row
#define NPULLQ 3              // ceil(NQUAD / NTH)

__device__ __forceinline__ float4 ld4(const float* p) { return *(const float4*)p; }
__device__ __forceinline__ void st4(float* p, float4 v) { *(float4*)p = v; }
__device__ __forceinline__ float2 ld2(const float* p) { return *(const float2*)p; }

__device__ __forceinline__ unsigned pack2(float c, float p) {
    _Float16 hc = (_Float16)c, hp = (_Float16)p;
    unsigned short uc, up;
    __builtin_memcpy(&uc, &hc, 2); __builtin_memcpy(&up, &hp, 2);
    return (unsigned)uc | ((unsigned)up << 16);
}
__device__ __forceinline__ float2 unpack2(unsigned v) {   // -> (C, P)
    unsigned short uc = (unsigned short)(v & 0xffffu), up = (unsigned short)(v >> 16);
    _Float16 hc, hp;
    __builtin_memcpy(&hc, &uc, 2); __builtin_memcpy(&hp, &up, 2);
    return make_float2((float)hc, (float)hp);
}

// 16B coherent (cross-XCD) store/load: same sc0 sc1 flags as agent atomics.
__device__ __forceinline__ void st_coh(unsigned* p, u32x4 v) {
    asm volatile("global_store_dwordx4 %0, %1, off sc0 sc1"
                 :: "v"(p), "v"(v) : "memory");
}
__device__ __forceinline__ u32x4 ld_coh(const unsigned* p) {
    u32x4 r;
    asm volatile("global_load_dwordx4 %0, %1, off sc0 sc1"
                 : "=v"(r) : "v"(p) : "memory");
    return r;
}

__device__ __forceinline__ float kcoef(const float* __restrict__ x, int gi, int gj) {
    float xp;
    if (gi < 55 || gi >= 457 || gj < 55 || gj >= 457)
        xp = 1e-6f;                                   // ABC pad
    else if (gi >= 128 && gi < 384 && gj >= 128 && gj < 384)
        xp = x[(gi - 128) * 256 + (gj - 128)];
    else
        xp = 1.5f;                                    // bg pad
    float t = 0.2f * xp;
    return t * t;
}

__device__ __forceinline__ int tile_sdist(int ti, int tj) {
    int lo = ti * TI - HALO, hi = lo + LT - 1;
    int di = WOFF < lo ? lo - WOFF : (WOFF > hi ? WOFF - hi : 0);
    lo = tj * TI - HALO; hi = lo + LT - 1;
    int dj = WOFF < lo ? lo - WOFF : (WOFF > hi ? WOFF - hi : 0);
    return di > dj ? di : dj;
}
__device__ __forceinline__ bool tile_live(int ti, int tj, int ph) {
    return tile_sdist(ti, tj) <= 2 * (ph * TS + TS) + 4;
}

__global__ __launch_bounds__(NTH, 1)
void persist_kernel(const float* __restrict__ x,
                    const float* __restrict__ src,
                    const int* __restrict__ meas,
                    const int* __restrict__ trans,
                    int* __restrict__ flags,
                    unsigned* __restrict__ GA, unsigned* __restrict__ GB,
                    float* __restrict__ out)
{
    __shared__ float lds0[LDSE];
    __shared__ float lds1[LDSE];
    const int tid  = threadIdx.x;
    const int b    = blockIdx.x;
    const int r    = b & 15;          // channel (tiles share b%8 -> one XCD)
    const int tile = b >> 4;
    const int tI   = tile >> 2, tJ = tile & 3;
    const int ri0  = tI * TI - HALO;
    const int rj0  = tJ * TI - HALO;

    const bool active = tid < NACT;
    const int ty = tid / 21, tx = tid - 21 * (tid / 21);
    const int li0 = 4 * ty, lj0 = 4 * tx;
    const bool inner = active && tx >= 4 && tx <= 16 && ty >= 4 && ty <= 16;

    // zero BOTH buffers (dead->live blocks rely on pristine-zero LDS)
    for (int q = tid; q < LDSE / 4; q += NTH) {
        st4(&lds0[q * 4], make_float4(0.f, 0.f, 0.f, 0.f));
        st4(&lds1[q * 4], make_float4(0.f, 0.f, 0.f, 0.f));
    }

    const int trv = trans[r];
    const int ox = (trv >> 9) - WOFF, oy = (trv & NMASK) - WOFF;

    // in-kernel out zeroing, part 1: tile-0 blocks zero out-of-window meas
    // entries of their channel (in-window entries are owned & fully written).
    if (tile == 0 && tid < NM) {
        int mc = meas[tid];
        int mi = ((mc >> 9)    - ox) & NMASK;
        int mj = ((mc & NMASK) - oy) & NMASK;
        if (mi >= WW || mj >= WW) {
            float* mo = out + (size_t)(r * NM + tid) * NT;
            #pragma unroll
            for (int s = 0; s < NT; ++s) mo[s] = 0.f;
        }
    }

    float C[16], P[16], K[16];
    #pragma unroll
    for (int i = 0; i < 16; ++i) { C[i] = 0.f; P[i] = 0.f; K[i] = 0.f; }

    int offT2 = 0, offT1 = 0, offB1 = 0, offB2 = 0;
    int offLp[4] = {0,0,0,0}, offRp[4] = {0,0,0,0}, offC[4] = {0,0,0,0};
    unsigned smask = 0;
    if (active) {
        #pragma unroll
        for (int rr = 0; rr < 4; ++rr) {
            int wr = ri0 + li0 + rr;
            #pragma unroll
            for (int cc = 0; cc < 4; ++cc) {
                int wc = rj0 + lj0 + cc;
                K[rr*4+cc] = kcoef(x, (ox + wr) & NMASK, (oy + wc) & NMASK);
            }
        }
        int rT2 = li0 - 2 < 0 ? 0 : li0 - 2;
        int rT1 = li0 - 1 < 0 ? 0 : li0 - 1;
        int rB1 = li0 + 4 > LT - 1 ? LT - 1 : li0 + 4;
        int rB2 = li0 + 5 > LT - 1 ? LT - 1 : li0 + 5;
        offT2 = rT2 * LTS + lj0;  offT1 = rT1 * LTS + lj0;
        offB1 = rB1 * LTS + lj0;  offB2 = rB2 * LTS + lj0;
        #pragma unroll
        for (int rr = 0; rr < 4; ++rr) {
            int base = (li0 + rr) * LTS + lj0;
            offC[rr] = base;
            int ol = base - 2;  if (ol < 0) ol = 0;           // 8B aligned
            int orr = base + 4; if (orr > LDSE - 2) orr = LDSE - 2;
            offLp[rr] = ol; offRp[rr] = orr;
        }
        int si = (WOFF - ri0) - li0, sj = (WOFF - rj0) - lj0;
        if (si >= 0 && si < 4 && sj >= 0 && sj < 4) smask = 1u << (si * 4 + sj);
    }

    bool mvalid = false; int mlds = 0; float* mout = nullptr;
    if (tid < NM) {
        int mc = meas[tid];
        int mi = ((mc >> 9)    - ox) & NMASK;
        int mj = ((mc & NMASK) - oy) & NMASK;
        int li = mi - ri0, lj = mj - rj0;
        mvalid = (li >= HALO && li < HALO + TI && lj >= HALO && lj < HALO + TI);
        mlds = li * LTS + lj;
        mout = out + (size_t)(r * NM + tid) * NT;
    }

    __syncthreads();

    auto step1 = [&](float (&A)[16], float (&B)[16],
                     const float* rd, float* wb, float sval, int jj) {
        if (active) {
            float t2[4], t1[4], b1a[4], b2a[4];
            float4 v;
            v = ld4(rd + offT2); t2[0]=v.x;  t2[1]=v.y;  t2[2]=v.z;  t2[3]=v.w;
            v = ld4(rd + offT1); t1[0]=v.x;  t1[1]=v.y;  t1[2]=v.z;  t1[3]=v.w;
            v = ld4(rd + offB1); b1a[0]=v.x; b1a[1]=v.y; b1a[2]=v.z; b1a[3]=v.w;
            v = ld4(rd + offB2); b2a[0]=v.x; b2a[1]=v.y; b2a[2]=v.z; b2a[3]=v.w;
            float2 lp[4], rp[4];
            #pragma unroll
            for (int rr = 0; rr < 4; ++rr) {
                lp[rr] = ld2(rd + offLp[rr]);   // cols -2,-1
                rp[rr] = ld2(rd + offRp[rr]);   // cols +4,+5
            }
            #pragma unroll
            for (int rr = 0; rr < 4; ++rr) {
                float h[8];
                h[0]=lp[rr].x; h[1]=lp[rr].y;
                h[2]=B[rr*4+0]; h[3]=B[rr*4+1]; h[4]=B[rr*4+2]; h[5]=B[rr*4+3];
                h[6]=rp[rr].x; h[7]=rp[rr].y;
                #pragma unroll
                for (int cc = 0; cc < 4; ++cc) {
                    float vm2 = (rr == 0) ? t2[cc]  : (rr == 1) ? t1[cc]  : B[(rr-2)*4+cc];
                    float vm1 = (rr == 0) ? t1[cc]  : B[(rr-1)*4+cc];
                    float vp1 = (rr == 3) ? b1a[cc] : B[(rr+1)*4+cc];
                    float vp2 = (rr == 3) ? b2a[cc] : (rr == 2) ? b1a[cc] : B[(rr+2)*4+cc];
                    float c0  = h[cc+2];
                    float lap = (16.f * (h[cc+1] + h[cc+3] + vm1 + vp1)
                                 - (h[cc] + h[cc+4] + vm2 + vp2)
                                 - 60.f * c0) * (1.f / 12.f);
                    float pn = 2.f * c0 - A[rr*4+cc] + K[rr*4+cc] * lap;
                    if (smask & (1u << (rr*4+cc))) pn += sval;
                    A[rr*4+cc] = pn;
                }
                st4(wb + offC[rr],
                    make_float4(A[rr*4+0], A[rr*4+1], A[rr*4+2], A[rr*4+3]));
            }
        }
        __syncthreads();
        if (mvalid) mout[jj] = wb[mlds];
    };

    for (int ph = 0; ph < NPHASE; ++ph) {
        const int J = ph * TS;
        const bool liveSelf = tile_live(tI, tJ, ph);
        unsigned* Wp = ((ph & 1) ? GB : GA) + (size_t)r * WCELLS;
        const bool bnd = ph < NPHASE - 1;
        if (liveSelf) {
            float sv[TS];
            #pragma unroll
            for (int s = 0; s < TS; ++s) sv[s] = 0.09f * src[J + s];
            step1(P, C, lds0, lds1, sv[0], J + 0);
            step1(C, P, lds1, lds0, sv[1], J + 1);
            step1(P, C, lds0, lds1, sv[2], J + 2);
            step1(C, P, lds1, lds0, sv[3], J + 3);
            step1(P, C, lds0, lds1, sv[4], J + 4);
            step1(C, P, lds1, lds0, sv[5], J + 5);
            step1(P, C, lds0, lds1, sv[6], J + 6);
            step1(C, P, lds1, lds0, sv[7], J + 7);
            // lds0 = f_{J+7} (valid [16,68)^2), lds1 = f_{J+6}
        } else if (mvalid) {
            // in-kernel out zeroing, part 2: dead owner writes exact zeros
            #pragma unroll
            for (int s = 0; s < TS; ++s) mout[J + s] = 0.f;
        }
        if (bnd) {
            if (liveSelf) {   // publish frame as fp16-packed cell QUADS (16B)
                for (int pf = tid; pf < FQUAD; pf += NTH) {
                    int row, col;
                    if (pf < FQUAD_A) {
                        int rA = pf / 13;
                        row = 16 + (rA < 16 ? rA : rA + 20);
                        col = 16 + 4 * (pf - 13 * rA);
                    } else {
                        int p2 = pf - FQUAD_A;
                        int rB = p2 >> 3;
                        int c  = p2 & 7;
                        row = 32 + rB;
                        col = c < 4 ? 16 + 4 * c : 4 * c + 36;   // 52..64
                    }
                    int l = row * LTS + col;
                    u32x4 v;
                    v.x = pack2(lds0[l],     lds1[l]);
                    v.y = pack2(lds0[l + 1], lds1[l + 1]);
                    v.z = pack2(lds0[l + 2], lds1[l + 2]);
                    v.w = pack2(lds0[l + 3], lds1[l + 3]);
                    int gw = (ri0 + row) * WW + (rj0 + col);     // %4 == 0
                    st_coh(&Wp[gw], v);
                }
                asm volatile("s_waitcnt vmcnt(0)" ::: "memory");
            }
            __syncthreads();
            if (liveSelf && tid == 0)
                __hip_atomic_store(&flags[ph * NBLK + b], 1,
                                   __ATOMIC_RELAXED, __HIP_MEMORY_SCOPE_AGENT);
            const bool liveNext = tile_live(tI, tJ, ph + 1);
            if (liveNext && tid < 9 && tid != 4) {     // spin on live neighbors
                int nti = tI + tid / 3 - 1, ntj = tJ + tid % 3 - 1;
                if ((unsigned)nti < 4u && (unsigned)ntj < 4u &&
                    tile_live(nti, ntj, ph)) {
                    int* f = &flags[ph * NBLK + ((((nti << 2) | ntj) << 4) | r)];
                    while (!__hip_atomic_load(f, __ATOMIC_RELAXED,
                                              __HIP_MEMORY_SCOPE_AGENT)) {}
                }
            }
            __syncthreads();
            if (liveNext) {
                // batched pull of halo quads (static reg indices), then LDS b128
                u32x4 vv[NPULLQ]; int ll[NPULLQ];
                #pragma unroll
                for (int k = 0; k < NPULLQ; ++k) {
                    vv[k].x = vv[k].y = vv[k].z = vv[k].w = 0u; ll[k] = -1;
                    int p = tid + k * NTH;
                    if (p < NQUAD) {
                        int row, col;
                        if (p < NQUAD_TB) {
                            int rT = p / 21;
                            row = rT < 16 ? rT : rT + 52;
                            col = 4 * (p - 21 * rT);
                        } else {
                            int p2 = p - NQUAD_TB;
                            int rM = p2 >> 3;
                            int c  = p2 & 7;
                            row = 16 + rM;
                            col = c < 4 ? 4 * c : 4 * c + 52;    // 68..80
                        }
                        ll[k] = row * LTS + col;
                        int nti = tI + (row < HALO ? -1 : (row >= HALO + TI ? 1 : 0));
                        int ntj = tJ + (col < HALO ? -1 : (col >= HALO + TI ? 1 : 0));
                        if ((unsigned)nti < 4u && (unsigned)ntj < 4u &&
                            tile_live(nti, ntj, ph)) {
                            int gw = (ri0 + row) * WW + (rj0 + col);
                            vv[k] = ld_coh(&Wp[gw]);
                        } else {
                            ll[k] = -ll[k] - 2;   // mark zero-fill (encode)
                        }
                    }
                }
                asm volatile("s_waitcnt vmcnt(0)" ::: "memory");
                #pragma unroll
                for (int k = 0; k < NPULLQ; ++k) {
                    int l = ll[k];
                    bool zf = false;
                    if (l < -1) { l = -l - 2; zf = true; }
                    if (l >= 0) {
                        float4 f0, f1;
                        if (zf) {
                            f0 = make_float4(0.f,0.f,0.f,0.f); f1 = f0;
                        } else {
                            float2 a = unpack2(vv[k].x), bq = unpack2(vv[k].y);
                            float2 c2 = unpack2(vv[k].z), d = unpack2(vv[k].w);
                            f0 = make_float4(a.x, bq.x, c2.x, d.x);
                            f1 = make_float4(a.y, bq.y, c2.y, d.y);
                        }
                        st4(&lds0[l], f0);
                        st4(&lds1[l], f1);
                    }
                }
                __syncthreads();
                if (active && !inner) {   // ring threads refill regs from LDS
                    #pragma unroll
                    for (int rr = 0; rr < 4; ++rr) {
                        float4 vc = ld4(&lds0[offC[rr]]);
                        float4 vp = ld4(&lds1[offC[rr]]);
                        C[rr*4+0]=vc.x; C[rr*4+1]=vc.y; C[rr*4+2]=vc.z; C[rr*4+3]=vc.w;
                        P[rr*4+0]=vp.x; P[rr*4+1]=vp.y; P[rr*4+2]=vp.z; P[rr*4+3]=vp.w;
                    }
                }
            }
        }
    }
}

extern "C" void kernel_launch(void* const* d_in, const int* in_sizes, int n_in,
                              void* d_out, int out_size, void* d_ws, size_t ws_size,
                              hipStream_t stream)
{
    const float* x     = (const float*)d_in[0];
    const float* src   = (const float*)d_in[1];
    const int*   meas  = (const int*)d_in[2];
    const int*   trans = (const int*)d_in[3];
    float* outp = (float*)d_out;

    int*      flags = (int*)d_ws;                       // NPHASE*NBLK ints
    unsigned* GA = (unsigned*)((char*)d_ws + 8192);     // 16B-aligned
    unsigned* GB = GA + (size_t)NCH * WCELLS;

    hipMemsetAsync(flags, 0, NPHASE * NBLK * sizeof(int), stream);

    persist_kernel<<<NBLK, NTH, 0, stream>>>(x, src, meas, trans, flags,
                                             GA, GB, outp);
}

// Round 18
// 69.707 us; speedup vs baseline: 1.0466x; 1.0037x over previous
//
#include <hip/hip_runtime.h>

// Wave forward: 16 channels, 208x208 window/channel, 48 steps, ONE persistent
// kernel. r16 protocol (3x3-neighborhood agent-scope flags, fp16-packed
// 16B-quad halo exchange via sc0 sc1, in-kernel out zeroing), but 4 phases x
// TS=12 (HALO=24, 100x84 tiles, 576 thr) -> 3 boundaries instead of 5.
// Grid stays 256 = 1 block/CU (deadlock-safe residency, proven r13-r16).

typedef unsigned long long u64;
typedef __attribute__((ext_vector_type(4))) unsigned int u32x4;

#define GN     512
#define NMASK  511
#define NCH    16
#define NT     48
#define NM     128
#define WW     208            // window size
#define WOFF   103            // source offset inside window
#define TI     52             // tile interior (rows & cols)
#define TS     12             // substeps per phase
#define NPHASE 4
#define HALO   24             // 2*TS
#define LTR    100            // tile rows (TI + 2*HALO)
#define LTC    84             // tile cols = LDS row stride
#define LDSE   (LTR*LTC)      // 8400 floats / buffer (33.6 KB; x2 = 67.2 KB)
#define WCELLS (WW*WW)        // 43264
#define NTH    576            // 9 waves
#define NACT   525            // 25x21 threads x 4x4 cells = 100x84
#define NBLK   256            // 16 tiles x 16 channels = 1 block/CU
#define FQUAD  676            // interior quads (52 rows x 13)
#define NQ_TB  1008           // top+bottom halo quads (48 rows x 21)
#define NQUAD  1632           // total halo quads (+ 52 rows x 12 mid)
#define NPULLQ 3              // ceil(1632/576)

__device__ __forceinline__ float4 ld4(const float* p) { return *(const float4*)p; }
__device__ __forceinline__ void st4(float* p, float4 v) { *(float4*)p = v; }
__device__ __forceinline__ float2 ld2(const float* p) { return *(const float2*)p; }

__device__ __forceinline__ unsigned pack2(float c, float p) {
    _Float16 hc = (_Float16)c, hp = (_Float16)p;
    unsigned short uc, up;
    __builtin_memcpy(&uc, &hc, 2); __builtin_memcpy(&up, &hp, 2);
    return (unsigned)uc | ((unsigned)up << 16);
}
__device__ __forceinline__ float2 unpack2(unsigned v) {   // -> (C, P)
    unsigned short uc = (unsigned short)(v & 0xffffu), up = (unsigned short)(v >> 16);
    _Float16 hc, hp;
    __builtin_memcpy(&hc, &uc, 2); __builtin_memcpy(&hp, &up, 2);
    return make_float2((float)hc, (float)hp);
}

// 16B coherent (cross-XCD) store/load: same sc0 sc1 flags as agent atomics.
__device__ __forceinline__ void st_coh(unsigned* p, u32x4 v) {
    asm volatile("global_store_dwordx4 %0, %1, off sc0 sc1"
                 :: "v"(p), "v"(v) : "memory");
}
__device__ __forceinline__ u32x4 ld_coh(const unsigned* p) {
    u32x4 r;
    asm volatile("global_load_dwordx4 %0, %1, off sc0 sc1"
                 : "=v"(r) : "v"(p) : "memory");
    return r;
}

__device__ __forceinline__ float kcoef(const float* __restrict__ x, int gi, int gj) {
    float xp;
    if (gi < 55 || gi >= 457 || gj < 55 || gj >= 457)
        xp = 1e-6f;                                   // ABC pad
    else if (gi >= 128 && gi < 384 && gj >= 128 && gj < 384)
        xp = x[(gi - 128) * 256 + (gj - 128)];
    else
        xp = 1.5f;                                    // bg pad
    float t = 0.2f * xp;
    return t * t;
}

// support-cone distance of a tile's 100x84 region to the source
__device__ __forceinline__ int tile_sdist(int ti, int tj) {
    int lo = ti * TI - HALO, hi = lo + LTR - 1;
    int di = WOFF < lo ? lo - WOFF : (WOFF > hi ? WOFF - hi : 0);
    lo = tj * TI - HALO; hi = lo + LTC - 1;
    int dj = WOFF < lo ? lo - WOFF : (WOFF > hi ? WOFF - hi : 0);
    return di > dj ? di : dj;
}
__device__ __forceinline__ bool tile_live(int ti, int tj, int ph) {
    return tile_sdist(ti, tj) <= 2 * (ph * TS + TS) + 4;
}

__global__ __launch_bounds__(NTH, 1)
void persist_kernel(const float* __restrict__ x,
                    const float* __restrict__ src,
                    const int* __restrict__ meas,
                    const int* __restrict__ trans,
                    int* __restrict__ flags,
                    unsigned* __restrict__ GA, unsigned* __restrict__ GB,
                    float* __restrict__ out)
{
    __shared__ float lds0[LDSE];
    __shared__ float lds1[LDSE];
    const int tid  = threadIdx.x;
    const int b    = blockIdx.x;
    const int r    = b & 15;          // channel
    const int tile = b >> 4;          // 0..15
    const int tIr  = tile >> 2, tIc = tile & 3;
    const int ri0  = tIr * TI - HALO;
    const int cj0  = tIc * TI - HALO;

    const bool active = tid < NACT;
    const int ty = tid / 21, tx = tid - 21 * (tid / 21);
    const int li0 = 4 * ty, lj0 = 4 * tx;
    const bool inner = active && tx >= 6 && tx <= 18 && ty >= 6 && ty <= 18;

    // zero BOTH buffers (dead->live blocks rely on pristine-zero LDS)
    for (int q = tid; q < LDSE / 4; q += NTH) {
        st4(&lds0[q * 4], make_float4(0.f, 0.f, 0.f, 0.f));
        st4(&lds1[q * 4], make_float4(0.f, 0.f, 0.f, 0.f));
    }

    const int trv = trans[r];
    const int ox = (trv >> 9) - WOFF, oy = (trv & NMASK) - WOFF;

    // out zeroing part 1: tile-0 blocks zero out-of-window meas entries
    if (tile == 0 && tid < NM) {
        int mc = meas[tid];
        int mi = ((mc >> 9)    - ox) & NMASK;
        int mj = ((mc & NMASK) - oy) & NMASK;
        if (mi >= WW || mj >= WW) {
            float* mo = out + (size_t)(r * NM + tid) * NT;
            #pragma unroll
            for (int s = 0; s < NT; ++s) mo[s] = 0.f;
        }
    }

    float C[16], P[16], K[16];
    #pragma unroll
    for (int i = 0; i < 16; ++i) { C[i] = 0.f; P[i] = 0.f; K[i] = 0.f; }

    int offT2 = 0, offT1 = 0, offB1 = 0, offB2 = 0;
    int offLp[4] = {0,0,0,0}, offRp[4] = {0,0,0,0}, offC[4] = {0,0,0,0};
    unsigned smask = 0;
    if (active) {
        #pragma unroll
        for (int rr = 0; rr < 4; ++rr) {
            int wr = ri0 + li0 + rr;
            #pragma unroll
            for (int cc = 0; cc < 4; ++cc) {
                int wc = cj0 + lj0 + cc;
                K[rr*4+cc] = kcoef(x, (ox + wr) & NMASK, (oy + wc) & NMASK);
            }
        }
        int rT2 = li0 - 2 < 0 ? 0 : li0 - 2;
        int rT1 = li0 - 1 < 0 ? 0 : li0 - 1;
        int rB1 = li0 + 4 > LTR - 1 ? LTR - 1 : li0 + 4;
        int rB2 = li0 + 5 > LTR - 1 ? LTR - 1 : li0 + 5;
        offT2 = rT2 * LTC + lj0;  offT1 = rT1 * LTC + lj0;
        offB1 = rB1 * LTC + lj0;  offB2 = rB2 * LTC + lj0;
        #pragma unroll
        for (int rr = 0; rr < 4; ++rr) {
            int base = (li0 + rr) * LTC + lj0;
            offC[rr] = base;
            int ol = base - 2;  if (ol < 0) ol = 0;           // 8B aligned
            int orr = base + 4; if (orr > LDSE - 2) orr = LDSE - 2;
            offLp[rr] = ol; offRp[rr] = orr;
        }
        int si = (WOFF - ri0) - li0, sj = (WOFF - cj0) - lj0;
        if (si >= 0 && si < 4 && sj >= 0 && sj < 4) smask = 1u << (si * 4 + sj);
    }

    bool mvalid = false; int mlds = 0; float* mout = nullptr;
    if (tid < NM) {
        int mc = meas[tid];
        int mi = ((mc >> 9)    - ox) & NMASK;
        int mj = ((mc & NMASK) - oy) & NMASK;
        int li = mi - ri0, lj = mj - cj0;
        mvalid = (li >= HALO && li < HALO + TI && lj >= HALO && lj < HALO + TI);
        mlds = li * LTC + lj;
        mout = out + (size_t)(r * NM + tid) * NT;
    }

    __syncthreads();

    auto step1 = [&](float (&A)[16], float (&B)[16],
                     const float* rd, float* wb, float sval, int jj) {
        if (active) {
            float t2[4], t1[4], b1a[4], b2a[4];
            float4 v;
            v = ld4(rd + offT2); t2[0]=v.x;  t2[1]=v.y;  t2[2]=v.z;  t2[3]=v.w;
            v = ld4(rd + offT1); t1[0]=v.x;  t1[1]=v.y;  t1[2]=v.z;  t1[3]=v.w;
            v = ld4(rd + offB1); b1a[0]=v.x; b1a[1]=v.y; b1a[2]=v.z; b1a[3]=v.w;
            v = ld4(rd + offB2); b2a[0]=v.x; b2a[1]=v.y; b2a[2]=v.z; b2a[3]=v.w;
            float2 lp[4], rp[4];
            #pragma unroll
            for (int rr = 0; rr < 4; ++rr) {
                lp[rr] = ld2(rd + offLp[rr]);   // cols -2,-1
                rp[rr] = ld2(rd + offRp[rr]);   // cols +4,+5
            }
            #pragma unroll
            for (int rr = 0; rr < 4; ++rr) {
                float h[8];
                h[0]=lp[rr].x; h[1]=lp[rr].y;
                h[2]=B[rr*4+0]; h[3]=B[rr*4+1]; h[4]=B[rr*4+2]; h[5]=B[rr*4+3];
                h[6]=rp[rr].x; h[7]=rp[rr].y;
                #pragma unroll
                for (int cc = 0; cc < 4; ++cc) {
                    float vm2 = (rr == 0) ? t2[cc]  : (rr == 1) ? t1[cc]  : B[(rr-2)*4+cc];
                    float vm1 = (rr == 0) ? t1[cc]  : B[(rr-1)*4+cc];
                    float vp1 = (rr == 3) ? b1a[cc] : B[(rr+1)*4+cc];
                    float vp2 = (rr == 3) ? b2a[cc] : (rr == 2) ? b1a[cc] : B[(rr+2)*4+cc];
                    float c0  = h[cc+2];
                    float lap = (16.f * (h[cc+1] + h[cc+3] + vm1 + vp1)
                                 - (h[cc] + h[cc+4] + vm2 + vp2)
                                 - 60.f * c0) * (1.f / 12.f);
                    float pn = 2.f * c0 - A[rr*4+cc] + K[rr*4+cc] * lap;
                    if (smask & (1u << (rr*4+cc))) pn += sval;
                    A[rr*4+cc] = pn;
                }
                st4(wb + offC[rr],
                    make_float4(A[rr*4+0], A[rr*4+1], A[rr*4+2], A[rr*4+3]));
            }
        }
        __syncthreads();
        if (mvalid) mout[jj] = wb[mlds];
    };

    for (int ph = 0; ph < NPHASE; ++ph) {
        const int J = ph * TS;
        const bool liveSelf = tile_live(tIr, tIc, ph);
        unsigned* Wp = ((ph & 1) ? GB : GA) + (size_t)r * WCELLS;
        const bool bnd = ph < NPHASE - 1;
        if (liveSelf) {
            float sv[TS];
            #pragma unroll
            for (int s = 0; s < TS; ++s) sv[s] = 0.09f * src[J + s];
            step1(P, C, lds0, lds1, sv[0],  J + 0);
            step1(C, P, lds1, lds0, sv[1],  J + 1);
            step1(P, C, lds0, lds1, sv[2],  J + 2);
            step1(C, P, lds1, lds0, sv[3],  J + 3);
            step1(P, C, lds0, lds1, sv[4],  J + 4);
            step1(C, P, lds1, lds0, sv[5],  J + 5);
            step1(P, C, lds0, lds1, sv[6],  J + 6);
            step1(C, P, lds1, lds0, sv[7],  J + 7);
            step1(P, C, lds0, lds1, sv[8],  J + 8);
            step1(C, P, lds1, lds0, sv[9],  J + 9);
            step1(P, C, lds0, lds1, sv[10], J + 10);
            step1(C, P, lds1, lds0, sv[11], J + 11);
            // lds0 = f_{J+11} (valid on interior [24,76)^2), lds1 = f_{J+10}
        } else if (mvalid) {
            #pragma unroll
            for (int s = 0; s < TS; ++s) mout[J + s] = 0.f;  // dead owner: zeros
        }
        if (bnd) {
            if (liveSelf) {   // publish full interior as fp16-packed quads (16B)
                for (int pf = tid; pf < FQUAD; pf += NTH) {
                    int rowq = pf / 13;
                    int row  = HALO + rowq;                   // 24..75
                    int col  = HALO + 4 * (pf - 13 * rowq);   // 24..72
                    int l = row * LTC + col;
                    u32x4 v;
                    v.x = pack2(lds0[l],     lds1[l]);
                    v.y = pack2(lds0[l + 1], lds1[l + 1]);
                    v.z = pack2(lds0[l + 2], lds1[l + 2]);
                    v.w = pack2(lds0[l + 3], lds1[l + 3]);
                    int gw = (ri0 + row) * WW + (cj0 + col);  // %4 == 0
                    st_coh(&Wp[gw], v);
                }
                asm volatile("s_waitcnt vmcnt(0)" ::: "memory");
            }
            __syncthreads();
            if (liveSelf && tid == 0)
                __hip_atomic_store(&flags[ph * NBLK + b], 1,
                                   __ATOMIC_RELAXED, __HIP_MEMORY_SCOPE_AGENT);
            const bool liveNext = tile_live(tIr, tIc, ph + 1);
            if (liveNext && tid < 9 && tid != 4) {     // spin on live neighbors
                int nti = tIr + tid / 3 - 1, ntj = tIc + tid % 3 - 1;
                if ((unsigned)nti < 4u && (unsigned)ntj < 4u &&
                    tile_live(nti, ntj, ph)) {
                    int* f = &flags[ph * NBLK + ((((nti << 2) | ntj) << 4) | r)];
                    while (!__hip_atomic_load(f, __ATOMIC_RELAXED,
                                              __HIP_MEMORY_SCOPE_AGENT)) {}
                }
            }
            __syncthreads();
            if (liveNext) {
                // batched pull of halo quads (static reg indices), then LDS b128
                u32x4 vv[NPULLQ]; int ll[NPULLQ];
                #pragma unroll
                for (int k = 0; k < NPULLQ; ++k) {
                    vv[k].x = vv[k].y = vv[k].z = vv[k].w = 0u; ll[k] = -1;
                    int p = tid + k * NTH;
                    if (p < NQUAD) {
                        int row, col;
                        if (p < NQ_TB) {
                            int rT = p / 21;
                            row = rT < HALO ? rT : rT + TI;     // 0..23, 76..99
                            col = 4 * (p - 21 * rT);
                        } else {
                            int q2 = p - NQ_TB;
                            int rM = q2 / 12;
                            int c  = q2 - 12 * rM;
                            row = HALO + rM;                    // 24..75
                            col = c < 6 ? 4 * c : 4 * c + TI;   // 0..20, 76..96
                        }
                        ll[k] = row * LTC + col;
                        int nti = tIr + (row < HALO ? -1 : (row >= HALO + TI ? 1 : 0));
                        int ntj = tIc + (col < HALO ? -1 : (col >= HALO + TI ? 1 : 0));
                        if ((unsigned)nti < 4u && (unsigned)ntj < 4u &&
                            tile_live(nti, ntj, ph)) {
                            int gw = (ri0 + row) * WW + (cj0 + col);
                            vv[k] = ld_coh(&Wp[gw]);
                        } else {
                            ll[k] = -ll[k] - 2;   // mark zero-fill
                        }
                    }
                }
                asm volatile("s_waitcnt vmcnt(0)" ::: "memory");
                #pragma unroll
                for (int k = 0; k < NPULLQ; ++k) {
                    int l = ll[k];
                    bool zf = false;
                    if (l < -1) { l = -l - 2; zf = true; }
                    if (l >= 0) {
                        float4 f0, f1;
                        if (zf) {
                            f0 = make_float4(0.f,0.f,0.f,0.f); f1 = f0;
                        } else {
                            float2 a = unpack2(vv[k].x), bq = unpack2(vv[k].y);
                            float2 c2 = unpack2(vv[k].z), d = unpack2(vv[k].w);
                            f0 = make_float4(a.x, bq.x, c2.x, d.x);
                            f1 = make_float4(a.y, bq.y, c2.y, d.y);
                        }
                        st4(&lds0[l], f0);
                        st4(&lds1[l], f1);
                    }
                }
                __syncthreads();
                if (active && !inner) {   // ring threads refill regs from LDS
                    #pragma unroll
                    for (int rr = 0; rr < 4; ++rr) {
                        float4 vc = ld4(&lds0[offC[rr]]);
                        float4 vp = ld4(&lds1[offC[rr]]);
                        C[rr*4+0]=vc.x; C[rr*4+1]=vc.y; C[rr*4+2]=vc.z; C[rr*4+3]=vc.w;
                        P[rr*4+0]=vp.x; P[rr*4+1]=vp.y; P[rr*4+2]=vp.z; P[rr*4+3]=vp.w;
                    }
                }
            }
        }
    }
}

extern "C" void kernel_launch(void* const* d_in, const int* in_sizes, int n_in,
                              void* d_out, int out_size, void* d_ws, size_t ws_size,
                              hipStream_t stream)
{
    const float* x     = (const float*)d_in[0];
    const float* src   = (const float*)d_in[1];
    const int*   meas  = (const int*)d_in[2];
    const int*   trans = (const int*)d_in[3];
    float* outp = (float*)d_out;

    int*      flags = (int*)d_ws;                       // 3*256 ints
    unsigned* GA = (unsigned*)((char*)d_ws + 16384);    // 16B-aligned
    unsigned* GB = GA + (size_t)NCH * WCELLS;

    hipMemsetAsync(flags, 0, (NPHASE - 1) * NBLK * sizeof(int), stream);

    persist_kernel<<<NBLK, NTH, 0, stream>>>(x, src, meas, trans, flags,
                                             GA, GB, outp);
}